// Round 2
// baseline (127.165 us; speedup 1.0000x reference)
//
#include <hip/hip_runtime.h>
#include <hip/hip_bf16.h>
#include <math.h>

#define VOCAB 50257
#define D 512
#define INV_SMOOTH 5.0f

// One wave per 2 cache rows per iteration: 4 independent float4 loads in
// flight, two interleaved butterfly reductions, exp+atomic split across
// lanes 0 and 1.
__global__ __launch_bounds__(256) void dist_scatter_kernel(
        const float* __restrict__ cache_h,
        const float* __restrict__ h_t,
        const int* __restrict__ word_ids,
        float* __restrict__ bins,
        int n_rows) {
    const int lane    = threadIdx.x & 63;
    const int wave    = (int)((blockIdx.x * blockDim.x + threadIdx.x) >> 6);
    const int n_waves = (int)((gridDim.x * blockDim.x) >> 6);

    const float4* ht4 = reinterpret_cast<const float4*>(h_t);
    const float4 b0 = ht4[lane];
    const float4 b1 = ht4[lane + 64];

    for (int row = wave * 2; row < n_rows; row += n_waves * 2) {
        const bool has2 = (row + 1) < n_rows;
        const float4* r0 = reinterpret_cast<const float4*>(cache_h + (size_t)row * D);
        const float4* r1 = reinterpret_cast<const float4*>(cache_h + (size_t)(has2 ? row + 1 : row) * D);
        // issue all 4 loads before any dependent math
        float4 a0 = r0[lane];
        float4 a1 = r0[lane + 64];
        float4 c0 = r1[lane];
        float4 c1 = r1[lane + 64];

        float dx, s0 = 0.0f, s1 = 0.0f;
        dx = a0.x - b0.x; s0 = fmaf(dx, dx, s0);
        dx = a0.y - b0.y; s0 = fmaf(dx, dx, s0);
        dx = a0.z - b0.z; s0 = fmaf(dx, dx, s0);
        dx = a0.w - b0.w; s0 = fmaf(dx, dx, s0);
        dx = a1.x - b1.x; s0 = fmaf(dx, dx, s0);
        dx = a1.y - b1.y; s0 = fmaf(dx, dx, s0);
        dx = a1.z - b1.z; s0 = fmaf(dx, dx, s0);
        dx = a1.w - b1.w; s0 = fmaf(dx, dx, s0);
        dx = c0.x - b0.x; s1 = fmaf(dx, dx, s1);
        dx = c0.y - b0.y; s1 = fmaf(dx, dx, s1);
        dx = c0.z - b0.z; s1 = fmaf(dx, dx, s1);
        dx = c0.w - b0.w; s1 = fmaf(dx, dx, s1);
        dx = c1.x - b1.x; s1 = fmaf(dx, dx, s1);
        dx = c1.y - b1.y; s1 = fmaf(dx, dx, s1);
        dx = c1.z - b1.z; s1 = fmaf(dx, dx, s1);
        dx = c1.w - b1.w; s1 = fmaf(dx, dx, s1);

        #pragma unroll
        for (int off = 32; off > 0; off >>= 1) {
            s0 += __shfl_xor(s0, off, 64);
            s1 += __shfl_xor(s1, off, 64);
        }
        // after the butterfly every lane holds the full sums
        if (lane == 0) {
            atomicAdd(&bins[word_ids[row]], expf(sqrtf(s0) * INV_SMOOTH));
        } else if (lane == 1 && has2) {
            atomicAdd(&bins[word_ids[row + 1]], expf(sqrtf(s1) * INV_SMOOTH));
        }
    }
}

// Single-block fused max + sum-exp -> lse.  bins = 200 KB, L2-resident.
__global__ __launch_bounds__(1024) void lse_kernel(const float* __restrict__ bins,
                                                   float* __restrict__ lse_out) {
    __shared__ float sm[16];
    const int tid  = threadIdx.x;
    const int lane = tid & 63, w = tid >> 6;

    float m = 0.0f;  // bins >= 0
    for (int i = tid; i < VOCAB; i += 1024) m = fmaxf(m, bins[i]);
    #pragma unroll
    for (int off = 32; off > 0; off >>= 1) m = fmaxf(m, __shfl_xor(m, off, 64));
    if (lane == 0) sm[w] = m;
    __syncthreads();
    if (tid < 16) {
        float mm = sm[tid];
        #pragma unroll
        for (int off = 8; off > 0; off >>= 1) mm = fmaxf(mm, __shfl_xor(mm, off, 64));
        if (tid == 0) sm[0] = mm;
    }
    __syncthreads();
    const float mv = sm[0];
    __syncthreads();

    float s = 0.0f;
    for (int i = tid; i < VOCAB; i += 1024) s += expf(bins[i] - mv);
    #pragma unroll
    for (int off = 32; off > 0; off >>= 1) s += __shfl_xor(s, off, 64);
    if (lane == 0) sm[w] = s;
    __syncthreads();
    if (tid < 16) {
        float ss = sm[tid];
        #pragma unroll
        for (int off = 8; off > 0; off >>= 1) ss += __shfl_xor(ss, off, 64);
        if (tid == 0) lse_out[0] = mv + logf(ss);
    }
}

__global__ void out_kernel(const float* __restrict__ bins,
                           const float* __restrict__ lse,
                           float* __restrict__ out) {
    const float l = *lse;
    const int i = blockIdx.x * blockDim.x + threadIdx.x;
    if (i < VOCAB) out[i] = bins[i] - l;
}

extern "C" void kernel_launch(void* const* d_in, const int* in_sizes, int n_in,
                              void* d_out, int out_size, void* d_ws, size_t ws_size,
                              hipStream_t stream) {
    const float* h_t      = (const float*)d_in[0];
    const float* cache_h  = (const float*)d_in[1];
    const int*   word_ids = (const int*)d_in[2];
    float* out = (float*)d_out;

    const int n_rows = in_sizes[2];  // N_CACHE

    float* bins = (float*)d_ws;          // [VOCAB]
    float* lse  = bins + VOCAB;          // [1]

    hipMemsetAsync(d_ws, 0, VOCAB * sizeof(float), stream);

    dist_scatter_kernel<<<2048, 256, 0, stream>>>(cache_h, h_t, word_ids, bins, n_rows);
    lse_kernel<<<1, 1024, 0, stream>>>(bins, lse);
    out_kernel<<<(VOCAB + 255) / 256, 256, 0, stream>>>(bins, lse, out);
}

// Round 3
// 117.283 us; speedup vs baseline: 1.0843x; 1.0843x over previous
//
#include <hip/hip_runtime.h>
#include <hip/hip_bf16.h>
#include <math.h>

#define VOCAB 50257
#define D 512
#define INV_SMOOTH 5.0f
#define NPART 128

// One wave per row, software-pipelined: issue next row's loads (+ its word id)
// before the current row's fma chain / butterfly / atomic tail, so the tail
// hides under the next loads' latency. Single tail path (no divergent split).
__global__ __launch_bounds__(256) void dist_scatter_kernel(
        const float* __restrict__ cache_h,
        const float* __restrict__ h_t,
        const int* __restrict__ word_ids,
        float* __restrict__ bins,
        int n_rows) {
    const int lane    = threadIdx.x & 63;
    const int wave    = (int)((blockIdx.x * blockDim.x + threadIdx.x) >> 6);
    const int n_waves = (int)((gridDim.x * blockDim.x) >> 6);

    const float4* ht4 = reinterpret_cast<const float4*>(h_t);
    const float4 b0 = ht4[lane];
    const float4 b1 = ht4[lane + 64];
    const float4* ch4 = reinterpret_cast<const float4*>(cache_h);

    int row = wave;
    if (row >= n_rows) return;
    {
        const float4* r = ch4 + (size_t)row * (D / 4);
        float4 a0 = r[lane];
        float4 a1 = r[lane + 64];
        int wid = word_ids[row];

        while (true) {
            const int  next      = row + n_waves;
            const bool have_next = next < n_rows;
            float4 c0, c1;
            int    nwid = 0;
            if (have_next) {                       // wave-uniform branch
                const float4* rn = ch4 + (size_t)next * (D / 4);
                c0   = rn[lane];                   // issued before the tail
                c1   = rn[lane + 64];
                nwid = word_ids[next];
            }

            float dx, s = 0.0f;
            dx = a0.x - b0.x; s = fmaf(dx, dx, s);
            dx = a0.y - b0.y; s = fmaf(dx, dx, s);
            dx = a0.z - b0.z; s = fmaf(dx, dx, s);
            dx = a0.w - b0.w; s = fmaf(dx, dx, s);
            dx = a1.x - b1.x; s = fmaf(dx, dx, s);
            dx = a1.y - b1.y; s = fmaf(dx, dx, s);
            dx = a1.z - b1.z; s = fmaf(dx, dx, s);
            dx = a1.w - b1.w; s = fmaf(dx, dx, s);
            #pragma unroll
            for (int off = 32; off > 0; off >>= 1)
                s += __shfl_xor(s, off, 64);
            if (lane == 0)
                atomicAdd(&bins[wid], expf(sqrtf(s) * INV_SMOOTH));

            if (!have_next) break;
            row = next; a0 = c0; a1 = c1; wid = nwid;
        }
    }
}

// Pass 1: 128 blocks, each computes (local max, local sum-exp) of its vocab
// chunk (bins are L2-resident after the scatter).
__global__ __launch_bounds__(256) void partial_lse_kernel(
        const float* __restrict__ bins, float2* __restrict__ partials) {
    const int chunk = (VOCAB + NPART - 1) / NPART;   // 393
    const int lo = blockIdx.x * chunk;
    const int hi = min(lo + chunk, VOCAB);
    const int tid  = threadIdx.x;
    const int lane = tid & 63, w = tid >> 6;
    __shared__ float sm[4];

    float m = 0.0f;                                   // bins >= 0
    for (int i = lo + tid; i < hi; i += 256) m = fmaxf(m, bins[i]);
    #pragma unroll
    for (int off = 32; off > 0; off >>= 1) m = fmaxf(m, __shfl_xor(m, off, 64));
    if (lane == 0) sm[w] = m;
    __syncthreads();
    const float mv = fmaxf(fmaxf(sm[0], sm[1]), fmaxf(sm[2], sm[3]));
    __syncthreads();

    float s = 0.0f;
    for (int i = lo + tid; i < hi; i += 256) s += expf(bins[i] - mv);
    #pragma unroll
    for (int off = 32; off > 0; off >>= 1) s += __shfl_xor(s, off, 64);
    if (lane == 0) sm[w] = s;
    __syncthreads();
    if (tid == 0)
        partials[blockIdx.x] = make_float2(mv, sm[0] + sm[1] + sm[2] + sm[3]);
}

// Pass 2: every block redundantly folds the 128 partials (cheap, L2-hot),
// then writes its 256 outputs.
__global__ __launch_bounds__(256) void out_kernel(
        const float* __restrict__ bins, const float2* __restrict__ partials,
        float* __restrict__ out) {
    const int tid  = threadIdx.x;
    const int lane = tid & 63, w = tid >> 6;
    __shared__ float sm[4];

    const float2 p = (tid < NPART) ? partials[tid] : make_float2(0.0f, 0.0f);
    float m = p.x;
    #pragma unroll
    for (int off = 32; off > 0; off >>= 1) m = fmaxf(m, __shfl_xor(m, off, 64));
    if (lane == 0) sm[w] = m;
    __syncthreads();
    const float M = fmaxf(fmaxf(sm[0], sm[1]), fmaxf(sm[2], sm[3]));
    __syncthreads();

    float s = (tid < NPART) ? p.y * expf(p.x - M) : 0.0f;
    #pragma unroll
    for (int off = 32; off > 0; off >>= 1) s += __shfl_xor(s, off, 64);
    if (lane == 0) sm[w] = s;
    __syncthreads();
    const float lse = M + logf(sm[0] + sm[1] + sm[2] + sm[3]);

    const int i = blockIdx.x * 256 + tid;
    if (i < VOCAB) out[i] = bins[i] - lse;
}

extern "C" void kernel_launch(void* const* d_in, const int* in_sizes, int n_in,
                              void* d_out, int out_size, void* d_ws, size_t ws_size,
                              hipStream_t stream) {
    const float* h_t      = (const float*)d_in[0];
    const float* cache_h  = (const float*)d_in[1];
    const int*   word_ids = (const int*)d_in[2];
    float* out = (float*)d_out;

    const int n_rows = in_sizes[2];  // N_CACHE

    float*  bins     = (float*)d_ws;                    // [VOCAB]
    float2* partials = (float2*)(bins + VOCAB + 1);     // [NPART] (aligned to 8B)

    hipMemsetAsync(d_ws, 0, VOCAB * sizeof(float), stream);

    dist_scatter_kernel<<<2048, 256, 0, stream>>>(cache_h, h_t, word_ids, bins, n_rows);
    partial_lse_kernel<<<NPART, 256, 0, stream>>>(bins, partials);
    out_kernel<<<(VOCAB + 255) / 256, 256, 0, stream>>>(bins, partials, out);
}

// Round 5
// 105.355 us; speedup vs baseline: 1.2070x; 1.1132x over previous
//
#include <hip/hip_runtime.h>
#include <hip/hip_bf16.h>
#include <math.h>

#define VOCAB 50257
#define D 512
#define INV_SMOOTH 5.0f
#define NPART 128

typedef float f32x4 __attribute__((ext_vector_type(4)));

// Half-wave per row: each 32-lane half owns one row (2 rows per wave per
// iteration). 4 float4 nontemporal loads per lane, 16 fmas, 5 butterfly
// stages shared by both halves, single branch with one atomic instruction
// (lanes 0 and 32 active together).
__global__ __launch_bounds__(256) void dist_scatter_kernel(
        const float* __restrict__ cache_h,
        const float* __restrict__ h_t,
        const int* __restrict__ word_ids,
        float* __restrict__ bins,
        int n_rows) {
    const int lane = threadIdx.x & 63;
    const int sub  = lane & 31;
    const int half = lane >> 5;
    const int wave    = (int)((blockIdx.x * blockDim.x + threadIdx.x) >> 6);
    const int n_waves = (int)((gridDim.x * blockDim.x) >> 6);

    const f32x4* ht4 = reinterpret_cast<const f32x4*>(h_t);
    const f32x4 b0 = ht4[sub];
    const f32x4 b1 = ht4[sub + 32];
    const f32x4 b2 = ht4[sub + 64];
    const f32x4 b3 = ht4[sub + 96];

    for (int r = wave * 2; r < n_rows; r += n_waves * 2) {
        int row = r + half;
        int rc  = row < n_rows ? row : n_rows - 1;   // defensive clamp
        const f32x4* rp = reinterpret_cast<const f32x4*>(cache_h + (size_t)rc * D);
        f32x4 a0 = __builtin_nontemporal_load(rp + sub);
        f32x4 a1 = __builtin_nontemporal_load(rp + sub + 32);
        f32x4 a2 = __builtin_nontemporal_load(rp + sub + 64);
        f32x4 a3 = __builtin_nontemporal_load(rp + sub + 96);

        float dx, s = 0.0f;
        dx = a0.x - b0.x; s = fmaf(dx, dx, s);
        dx = a0.y - b0.y; s = fmaf(dx, dx, s);
        dx = a0.z - b0.z; s = fmaf(dx, dx, s);
        dx = a0.w - b0.w; s = fmaf(dx, dx, s);
        dx = a1.x - b1.x; s = fmaf(dx, dx, s);
        dx = a1.y - b1.y; s = fmaf(dx, dx, s);
        dx = a1.z - b1.z; s = fmaf(dx, dx, s);
        dx = a1.w - b1.w; s = fmaf(dx, dx, s);
        dx = a2.x - b2.x; s = fmaf(dx, dx, s);
        dx = a2.y - b2.y; s = fmaf(dx, dx, s);
        dx = a2.z - b2.z; s = fmaf(dx, dx, s);
        dx = a2.w - b2.w; s = fmaf(dx, dx, s);
        dx = a3.x - b3.x; s = fmaf(dx, dx, s);
        dx = a3.y - b3.y; s = fmaf(dx, dx, s);
        dx = a3.z - b3.z; s = fmaf(dx, dx, s);
        dx = a3.w - b3.w; s = fmaf(dx, dx, s);

        // 5 stages, both halves reduced simultaneously (offsets stay < 32)
        #pragma unroll
        for (int off = 16; off > 0; off >>= 1)
            s += __shfl_xor(s, off, 64);

        if (sub == 0 && row < n_rows) {
            atomicAdd(&bins[word_ids[row]], expf(sqrtf(s) * INV_SMOOTH));
        }
    }
}

// Pass 1: 128 blocks, each computes (local max, local sum-exp) of its chunk.
__global__ __launch_bounds__(256) void partial_lse_kernel(
        const float* __restrict__ bins, float2* __restrict__ partials) {
    const int chunk = (VOCAB + NPART - 1) / NPART;   // 393
    const int lo = blockIdx.x * chunk;
    const int hi = min(lo + chunk, VOCAB);
    const int tid  = threadIdx.x;
    const int lane = tid & 63, w = tid >> 6;
    __shared__ float sm[4];

    float m = 0.0f;                                   // bins >= 0
    for (int i = lo + tid; i < hi; i += 256) m = fmaxf(m, bins[i]);
    #pragma unroll
    for (int off = 32; off > 0; off >>= 1) m = fmaxf(m, __shfl_xor(m, off, 64));
    if (lane == 0) sm[w] = m;
    __syncthreads();
    const float mv = fmaxf(fmaxf(sm[0], sm[1]), fmaxf(sm[2], sm[3]));
    __syncthreads();

    float s = 0.0f;
    for (int i = lo + tid; i < hi; i += 256) s += expf(bins[i] - mv);
    #pragma unroll
    for (int off = 32; off > 0; off >>= 1) s += __shfl_xor(s, off, 64);
    if (lane == 0) sm[w] = s;
    __syncthreads();
    if (tid == 0)
        partials[blockIdx.x] = make_float2(mv, sm[0] + sm[1] + sm[2] + sm[3]);
}

// Pass 2: every block redundantly folds the 128 partials, writes 256 outputs.
__global__ __launch_bounds__(256) void out_kernel(
        const float* __restrict__ bins, const float2* __restrict__ partials,
        float* __restrict__ out) {
    const int tid  = threadIdx.x;
    const int lane = tid & 63, w = tid >> 6;
    __shared__ float sm[4];

    const float2 p = (tid < NPART) ? partials[tid] : make_float2(0.0f, 0.0f);
    float m = p.x;
    #pragma unroll
    for (int off = 32; off > 0; off >>= 1) m = fmaxf(m, __shfl_xor(m, off, 64));
    if (lane == 0) sm[w] = m;
    __syncthreads();
    const float M = fmaxf(fmaxf(sm[0], sm[1]), fmaxf(sm[2], sm[3]));
    __syncthreads();

    float s = (tid < NPART) ? p.y * expf(p.x - M) : 0.0f;
    #pragma unroll
    for (int off = 32; off > 0; off >>= 1) s += __shfl_xor(s, off, 64);
    if (lane == 0) sm[w] = s;
    __syncthreads();
    const float lse = M + logf(sm[0] + sm[1] + sm[2] + sm[3]);

    const int i = blockIdx.x * 256 + tid;
    if (i < VOCAB) out[i] = bins[i] - lse;
}

extern "C" void kernel_launch(void* const* d_in, const int* in_sizes, int n_in,
                              void* d_out, int out_size, void* d_ws, size_t ws_size,
                              hipStream_t stream) {
    const float* h_t      = (const float*)d_in[0];
    const float* cache_h  = (const float*)d_in[1];
    const int*   word_ids = (const int*)d_in[2];
    float* out = (float*)d_out;

    const int n_rows = in_sizes[2];  // N_CACHE

    float*  bins     = (float*)d_ws;                    // [VOCAB]
    float2* partials = (float2*)(bins + VOCAB + 1);     // [NPART] (8B aligned)

    (void)hipMemsetAsync(d_ws, 0, VOCAB * sizeof(float), stream);

    dist_scatter_kernel<<<2048, 256, 0, stream>>>(cache_h, h_t, word_ids, bins, n_rows);
    partial_lse_kernel<<<NPART, 256, 0, stream>>>(bins, partials);
    out_kernel<<<(VOCAB + 255) / 256, 256, 0, stream>>>(bins, partials, out);
}